// Round 8
// baseline (83.075 us; speedup 1.0000x reference)
//
#include <hip/hip_runtime.h>
#include <hip/hip_bf16.h>

#define NROWS 8192
#define DIM 256
#define NSPLIT 16
#define JSPAN (NROWS / NSPLIT)   /* 512 cols per block */
#define NGRP (JSPAN / 16)        /* 32 16-col groups per block */
#define RPW 64                   /* rows per wave (A stationary) */
#define RPB 256                  /* rows per block (4 waves) */

typedef __bf16 bf16x8 __attribute__((ext_vector_type(8)));
typedef float f32x4 __attribute__((ext_vector_type(4)));

#define NEG_LOG2E -1.4426950408889634f
#define NEG_LN2   -0.6931471805599453f

// ---- Kernel 1: L2-normalize rows of both inputs, fp32 -> bf16; zero accums ----
// En rows are additionally scaled by -log2(e) so the GEMM directly produces
// acc = -log2e * sim  ->  exp(-sim) = exp2(acc).
__global__ __launch_bounds__(256) void k_normalize_all(const float* __restrict__ emb,
                                                       const float* __restrict__ qry,
                                                       __hip_bfloat16* __restrict__ En,
                                                       __hip_bfloat16* __restrict__ Qn,
                                                       float* __restrict__ rowsum,
                                                       float* __restrict__ out) {
    if (blockIdx.x < 8)
        reinterpret_cast<float4*>(rowsum)[blockIdx.x * 256 + threadIdx.x] =
            float4{0.f, 0.f, 0.f, 0.f};
    if (blockIdx.x == 8 && threadIdx.x == 0) out[0] = 0.f;

    const int gr   = blockIdx.x * 4 + (threadIdx.x >> 6);
    const int lane = threadIdx.x & 63;
    const float* in;
    __hip_bfloat16* outp;
    int row;
    float scale;
    if (gr < NROWS) { in = emb; outp = En; row = gr;         scale = NEG_LOG2E; }
    else            { in = qry; outp = Qn; row = gr - NROWS; scale = 1.0f; }
    const float4 v = reinterpret_cast<const float4*>(in + (size_t)row * DIM)[lane];
    float ss = v.x * v.x + v.y * v.y + v.z * v.z + v.w * v.w;
#pragma unroll
    for (int m = 32; m >= 1; m >>= 1) ss += __shfl_xor(ss, m, 64);
    const float inv = scale / fmaxf(sqrtf(ss), 1e-8f);
    __hip_bfloat16 o[4];
    o[0] = __float2bfloat16(v.x * inv);
    o[1] = __float2bfloat16(v.y * inv);
    o[2] = __float2bfloat16(v.z * inv);
    o[3] = __float2bfloat16(v.w * inv);
    reinterpret_cast<ushort4*>(outp + (size_t)row * DIM)[lane] = *reinterpret_cast<const ushort4*>(o);
}

// ---- Kernel 2: fused sim-GEMM + row sum of exp(-s), NO LDS / NO BARRIERS ----
// 4 waves/block; each wave owns 64 stationary A-rows in registers (a[4][8],
// 128 VGPR) and streams its 512-col B slice straight from global (L2-resident:
// same-jq blocks land on the same XCD since XCD = bid%8 and jq = bid&15).
// B is 2-deep register-pipelined (named b0/b1 - static indexing, rule #20):
// the 8 dwordx4 loads of group p+1 fly under group p's 32 MFMAs. Each wave is
// an independent stream - no intra-block synchronization at all; the 2
// waves/SIMD drift freely and cover each other's load latency and epilogue.
__global__ __launch_bounds__(256, 2) void k_simlse(const __hip_bfloat16* __restrict__ En,
                                                   const __hip_bfloat16* __restrict__ Qn,
                                                   float* __restrict__ rowsum,
                                                   float* __restrict__ pickv) {
    const int bx   = blockIdx.x;
    const int ib   = bx >> 4;
    const int jq   = bx & 15;
    const int tid  = threadIdx.x;
    const int lane = tid & 63;
    const int w    = tid >> 6;
    const int l15  = lane & 15;
    const int lks  = lane >> 4;          // k-segment 0..3
    const int i0w  = ib * RPB + w * RPW;

    // A fragments: 64 rows x K=256 -> a[4][8] (128 regs).
    bf16x8 a[4][8];
    {
        const __hip_bfloat16* ab = En + (size_t)(i0w + l15) * DIM + lks * 8;
#pragma unroll
        for (int mi = 0; mi < 4; ++mi)
#pragma unroll
            for (int kk = 0; kk < 8; ++kk)
                a[mi][kk] = *reinterpret_cast<const bf16x8*>(ab + mi * 16 * DIM + kk * 32);
    }

    float racc[4][4];
#pragma unroll
    for (int mi = 0; mi < 4; ++mi)
#pragma unroll
        for (int r = 0; r < 4; ++r) racc[mi][r] = 0.0f;

    const int jq0 = jq * JSPAN;
    // Per-lane B base: col = jq0 + p*16 + l15, byte-in-col = kk*64 + lks*16.
    // (Wave reads 16 cols x 64 contiguous bytes per load inst - 64B sectors.)
    const char* qcol = (const char*)Qn + (size_t)jq0 * 512 + (size_t)l15 * 512 + lks * 16;

    auto loadB = [&](bf16x8 (&b)[8], int p) {
        const char* cb = qcol + (size_t)p * (16 * 512);
#pragma unroll
        for (int kk = 0; kk < 8; ++kk)
            b[kk] = *reinterpret_cast<const bf16x8*>(cb + kk * 64);
    };

    // MFMA group p + immediate exp2 epilogue.
    // C/D layout: col = lane&15, row = (lane>>4)*4 + r. acc = -log2e*s.
    auto step = [&](const bf16x8 (&b)[8], int p) {
        f32x4 acc[4];
#pragma unroll
        for (int mi = 0; mi < 4; ++mi) acc[mi] = f32x4{0.f, 0.f, 0.f, 0.f};

        __builtin_amdgcn_s_setprio(1);
#pragma unroll
        for (int kk = 0; kk < 8; ++kk)
#pragma unroll
            for (int mi = 0; mi < 4; ++mi)
                acc[mi] = __builtin_amdgcn_mfma_f32_16x16x32_bf16(
                    a[mi][kk], b[kk], acc[mi], 0, 0, 0);
        __builtin_amdgcn_s_setprio(0);

        const int grpbase = jq0 + p * 16;
        const bool spec = (grpbase <= i0w + RPW) && (grpbase + 16 > i0w);
        if (!spec) {
#pragma unroll
            for (int mi = 0; mi < 4; ++mi)
#pragma unroll
                for (int r = 0; r < 4; ++r)
                    racc[mi][r] += __builtin_amdgcn_exp2f(acc[mi][r]);
        } else {
            const int jg = grpbase + l15;
#pragma unroll
            for (int mi = 0; mi < 4; ++mi) {
                const int ig0 = i0w + mi * 16 + lks * 4;
#pragma unroll
                for (int r = 0; r < 4; ++r) {
                    const float e  = __builtin_amdgcn_exp2f(acc[mi][r]);
                    const int   ig = ig0 + r;
                    racc[mi][r] += (jg == ig) ? 0.0f : e;
                    const int pc = (ig == NROWS - 1) ? (NROWS - 2) : (ig + 1);
                    if (jg == pc) pickv[ig] = acc[mi][r] * NEG_LN2;  // recover s
                }
            }
        }
    };

    // 2-deep register pipeline over the 32 groups.
    bf16x8 b0[8], b1[8];
    loadB(b0, 0);
    for (int p = 0; p < NGRP; p += 2) {
        loadB(b1, p + 1);
        step(b0, p);
        if (p + 2 < NGRP) loadB(b0, p + 2);
        step(b1, p + 1);
    }

    // Reduce row partials across the 16 col-lanes, one atomicAdd per row.
#pragma unroll
    for (int mi = 0; mi < 4; ++mi)
#pragma unroll
        for (int r = 0; r < 4; ++r) {
            float v = racc[mi][r];
            v += __shfl_xor(v, 1, 64);
            v += __shfl_xor(v, 2, 64);
            v += __shfl_xor(v, 4, 64);
            v += __shfl_xor(v, 8, 64);
            if (l15 == 0) atomicAdd(&rowsum[i0w + mi * 16 + lks * 4 + r], v);
        }
}

// ---- Kernel 3: final reduce, 16 blocks, one atomicAdd each (out pre-zeroed) ----
__global__ __launch_bounds__(256) void k_finalize(const float* __restrict__ rowsum,
                                                  const float* __restrict__ pickv,
                                                  float* __restrict__ out) {
    __shared__ float red[4];
    const int base = blockIdx.x * 512;
    float s = 0.0f;
#pragma unroll
    for (int it = 0; it < 2; ++it) {
        const int i = base + it * 256 + threadIdx.x;
        s += __logf(rowsum[i]) + pickv[i];
    }
#pragma unroll
    for (int m = 32; m >= 1; m >>= 1) s += __shfl_xor(s, m, 64);
    if ((threadIdx.x & 63) == 0) red[threadIdx.x >> 6] = s;
    __syncthreads();
    if (threadIdx.x == 0)
        atomicAdd(out, (red[0] + red[1] + red[2] + red[3]) * (1.0f / (float)NROWS));
}

extern "C" void kernel_launch(void* const* d_in, const int* in_sizes, int n_in,
                              void* d_out, int out_size, void* d_ws, size_t ws_size,
                              hipStream_t stream) {
    const float* emb = (const float*)d_in[0];
    const float* qry = (const float*)d_in[1];
    float* out = (float*)d_out;

    char* ws = (char*)d_ws;
    __hip_bfloat16* En = (__hip_bfloat16*)ws;                                  // 4 MB
    __hip_bfloat16* Qn = (__hip_bfloat16*)(ws + (size_t)NROWS * DIM * 2);      // 4 MB
    float* rowsum = (float*)(ws + (size_t)NROWS * DIM * 4);                    // 32 KB
    float* pickv  = rowsum + NROWS;                                            // 32 KB

    k_normalize_all<<<2 * NROWS / 4, 256, 0, stream>>>(emb, qry, En, Qn, rowsum, out);
    k_simlse<<<32 * NSPLIT, 256, 0, stream>>>(En, Qn, rowsum, pickv);
    k_finalize<<<16, 256, 0, stream>>>(rowsum, pickv, out);
}

// Round 9
// 53.357 us; speedup vs baseline: 1.5570x; 1.5570x over previous
//
#include <hip/hip_runtime.h>
#include <hip/hip_bf16.h>

#define NROWS 8192
#define DIM 256
#define NSPLIT 16
#define JSPAN (NROWS / NSPLIT)   /* 512 cols per block */
#define NGRP (JSPAN / 16)        /* 32 16-col groups per wave */
#define RPW 64                   /* rows per wave (A stationary) */
#define RPB 256                  /* rows per block (4 waves) */
#define GRP_BYTES 8192           /* 16 cols x 512 B */

typedef __bf16 bf16x8 __attribute__((ext_vector_type(8)));
typedef float f32x4 __attribute__((ext_vector_type(4)));

#define NEG_LOG2E -1.4426950408889634f
#define NEG_LN2   -0.6931471805599453f

// ---- Kernel 1: L2-normalize rows of both inputs, fp32 -> bf16; zero accums ----
// En rows are additionally scaled by -log2(e) so the GEMM directly produces
// acc = -log2e * sim  ->  exp(-sim) = exp2(acc).
__global__ __launch_bounds__(256) void k_normalize_all(const float* __restrict__ emb,
                                                       const float* __restrict__ qry,
                                                       __hip_bfloat16* __restrict__ En,
                                                       __hip_bfloat16* __restrict__ Qn,
                                                       float* __restrict__ rowsum,
                                                       float* __restrict__ out) {
    if (blockIdx.x < 8)
        reinterpret_cast<float4*>(rowsum)[blockIdx.x * 256 + threadIdx.x] =
            float4{0.f, 0.f, 0.f, 0.f};
    if (blockIdx.x == 8 && threadIdx.x == 0) out[0] = 0.f;

    const int gr   = blockIdx.x * 4 + (threadIdx.x >> 6);
    const int lane = threadIdx.x & 63;
    const float* in;
    __hip_bfloat16* outp;
    int row;
    float scale;
    if (gr < NROWS) { in = emb; outp = En; row = gr;         scale = NEG_LOG2E; }
    else            { in = qry; outp = Qn; row = gr - NROWS; scale = 1.0f; }
    const float4 v = reinterpret_cast<const float4*>(in + (size_t)row * DIM)[lane];
    float ss = v.x * v.x + v.y * v.y + v.z * v.z + v.w * v.w;
#pragma unroll
    for (int m = 32; m >= 1; m >>= 1) ss += __shfl_xor(ss, m, 64);
    const float inv = scale / fmaxf(sqrtf(ss), 1e-8f);
    __hip_bfloat16 o[4];
    o[0] = __float2bfloat16(v.x * inv);
    o[1] = __float2bfloat16(v.y * inv);
    o[2] = __float2bfloat16(v.z * inv);
    o[3] = __float2bfloat16(v.w * inv);
    reinterpret_cast<ushort4*>(outp + (size_t)row * DIM)[lane] = *reinterpret_cast<const ushort4*>(o);
}

// Stage one 16-col group (8 KB) into THIS WAVE's private LDS buffer, 8 DMA
// calls of 1 KB. LDS dest is wave-uniform (HW adds lane*16); swizzle is
// applied on the SOURCE address (involution XOR of byte bits 4..6 with
// local-col&7) so the swizzled ds_read recovers linear data (G21).
__device__ __forceinline__ void stage_group(const char* __restrict__ qbase,
                                            char* wbuf, int p, int lane) {
    const int l31 = lane & 31;
    const int hi  = lane >> 5;
#pragma unroll
    for (int rr = 0; rr < 8; ++rr) {
        const int cl = 2 * rr + hi;              // local col 0..15
        const char* src = qbase + ((size_t)p * 16 + cl) * 512
                          + ((l31 * 16) ^ ((cl & 7) << 4));
        __builtin_amdgcn_global_load_lds(
            (const __attribute__((address_space(1))) void*)src,
            (__attribute__((address_space(3))) void*)(wbuf + rr * 1024), 16, 0, 0);
    }
}

// ---- Kernel 2: fused sim-GEMM + row sum of exp(-s) ----
// ZERO barriers. Each wave owns 64 stationary A-rows (a[4][8], 128 VGPR) and
// pipelines its own 16-col B groups through a PRIVATE 2x8KB LDS double buffer
// via global_load_lds. vmcnt counts only this wave's DMAs, so the per-group
// wait is a counted vmcnt(8) (never 0 until the tail) - T4 without the
// block-wide barrier that phase-locked rounds 2-6. Waves drift freely; the
// 8 waves/CU cover each other's LDS latency and exp2 epilogue.
__global__ __launch_bounds__(256, 2) void k_simlse(const __hip_bfloat16* __restrict__ En,
                                                   const __hip_bfloat16* __restrict__ Qn,
                                                   float* __restrict__ rowsum,
                                                   float* __restrict__ pickv) {
    __shared__ char lds[4][2][GRP_BYTES];   // [wave][buf] -> 64 KB/block
    const int bx   = blockIdx.x;
    const int ib   = bx >> 4;
    const int jq   = bx & 15;
    const int tid  = threadIdx.x;
    const int lane = tid & 63;
    const int w    = tid >> 6;
    const int l15  = lane & 15;
    const int lks  = lane >> 4;          // k-segment 0..3
    const int i0w  = ib * RPB + w * RPW;

    char* wbuf0 = lds[w][0];
    char* wbuf1 = lds[w][1];

    // A fragments: 64 rows x K=256 -> a[4][8] (128 regs).
    bf16x8 a[4][8];
    {
        const __hip_bfloat16* ab = En + (size_t)(i0w + l15) * DIM + lks * 8;
#pragma unroll
        for (int mi = 0; mi < 4; ++mi)
#pragma unroll
            for (int kk = 0; kk < 8; ++kk)
                a[mi][kk] = *reinterpret_cast<const bf16x8*>(ab + mi * 16 * DIM + kk * 32);
    }

    float racc[4][4];
#pragma unroll
    for (int mi = 0; mi < 4; ++mi)
#pragma unroll
        for (int r = 0; r < 4; ++r) racc[mi][r] = 0.0f;

    const int jq0 = jq * JSPAN;
    const char* qbase = (const char*)Qn + (size_t)jq0 * 512;

    // Prologue: stage groups 0 and 1 into this wave's two buffers.
    stage_group(qbase, wbuf0, 0, lane);
    stage_group(qbase, wbuf1, 1, lane);

    const int swz = (l15 & 7) << 4;

    for (int p = 0; p < NGRP; ++p) {
        // Counted private wait: all but the 8 newest DMAs done => group p
        // resident. Only the very last group (nothing behind it) drains to 0.
        if (p == NGRP - 1) asm volatile("s_waitcnt vmcnt(0)" ::: "memory");
        else               asm volatile("s_waitcnt vmcnt(8)" ::: "memory");
        __builtin_amdgcn_sched_barrier(0);

        // ds_read this group's B fragments (2-way bank aliasing only).
        const char* cb = ((p & 1) ? wbuf1 : wbuf0) + l15 * 512;
        bf16x8 b[8];
#pragma unroll
        for (int kk = 0; kk < 8; ++kk)
            b[kk] = *reinterpret_cast<const bf16x8*>(cb + ((kk * 64 + lks * 16) ^ swz));

        // b must be in registers before the DMA below overwrites this buffer.
        asm volatile("s_waitcnt lgkmcnt(0)" ::: "memory");
        __builtin_amdgcn_sched_barrier(0);

        if (p + 2 < NGRP)
            stage_group(qbase, (p & 1) ? wbuf1 : wbuf0, p + 2, lane);

        f32x4 acc[4];
#pragma unroll
        for (int mi = 0; mi < 4; ++mi) acc[mi] = f32x4{0.f, 0.f, 0.f, 0.f};

        __builtin_amdgcn_s_setprio(1);
#pragma unroll
        for (int kk = 0; kk < 8; ++kk)
#pragma unroll
            for (int mi = 0; mi < 4; ++mi)
                acc[mi] = __builtin_amdgcn_mfma_f32_16x16x32_bf16(
                    a[mi][kk], b[kk], acc[mi], 0, 0, 0);
        __builtin_amdgcn_s_setprio(0);

        // Epilogue. acc = -log2e*s; exp(-s) = exp2(acc).
        // C/D layout: col = lane&15, row = (lane>>4)*4 + r.
        const int grpbase = jq0 + p * 16;
        const bool spec = (grpbase <= i0w + RPW) && (grpbase + 16 > i0w);
        if (!spec) {
#pragma unroll
            for (int mi = 0; mi < 4; ++mi)
#pragma unroll
                for (int r = 0; r < 4; ++r)
                    racc[mi][r] += __builtin_amdgcn_exp2f(acc[mi][r]);
        } else {
            const int jg = grpbase + l15;
#pragma unroll
            for (int mi = 0; mi < 4; ++mi) {
                const int ig0 = i0w + mi * 16 + lks * 4;
#pragma unroll
                for (int r = 0; r < 4; ++r) {
                    const float e  = __builtin_amdgcn_exp2f(acc[mi][r]);
                    const int   ig = ig0 + r;
                    racc[mi][r] += (jg == ig) ? 0.0f : e;
                    const int pc = (ig == NROWS - 1) ? (NROWS - 2) : (ig + 1);
                    if (jg == pc) pickv[ig] = acc[mi][r] * NEG_LN2;  // recover s
                }
            }
        }
    }

    // Reduce row partials across the 16 col-lanes, one atomicAdd per row.
#pragma unroll
    for (int mi = 0; mi < 4; ++mi)
#pragma unroll
        for (int r = 0; r < 4; ++r) {
            float v = racc[mi][r];
            v += __shfl_xor(v, 1, 64);
            v += __shfl_xor(v, 2, 64);
            v += __shfl_xor(v, 4, 64);
            v += __shfl_xor(v, 8, 64);
            if (l15 == 0) atomicAdd(&rowsum[i0w + mi * 16 + lks * 4 + r], v);
        }
}

// ---- Kernel 3: final reduce, 16 blocks, one atomicAdd each (out pre-zeroed) ----
__global__ __launch_bounds__(256) void k_finalize(const float* __restrict__ rowsum,
                                                  const float* __restrict__ pickv,
                                                  float* __restrict__ out) {
    __shared__ float red[4];
    const int base = blockIdx.x * 512;
    float s = 0.0f;
#pragma unroll
    for (int it = 0; it < 2; ++it) {
        const int i = base + it * 256 + threadIdx.x;
        s += __logf(rowsum[i]) + pickv[i];
    }
#pragma unroll
    for (int m = 32; m >= 1; m >>= 1) s += __shfl_xor(s, m, 64);
    if ((threadIdx.x & 63) == 0) red[threadIdx.x >> 6] = s;
    __syncthreads();
    if (threadIdx.x == 0)
        atomicAdd(out, (red[0] + red[1] + red[2] + red[3]) * (1.0f / (float)NROWS));
}

extern "C" void kernel_launch(void* const* d_in, const int* in_sizes, int n_in,
                              void* d_out, int out_size, void* d_ws, size_t ws_size,
                              hipStream_t stream) {
    const float* emb = (const float*)d_in[0];
    const float* qry = (const float*)d_in[1];
    float* out = (float*)d_out;

    char* ws = (char*)d_ws;
    __hip_bfloat16* En = (__hip_bfloat16*)ws;                                  // 4 MB
    __hip_bfloat16* Qn = (__hip_bfloat16*)(ws + (size_t)NROWS * DIM * 2);      // 4 MB
    float* rowsum = (float*)(ws + (size_t)NROWS * DIM * 4);                    // 32 KB
    float* pickv  = rowsum + NROWS;                                            // 32 KB

    k_normalize_all<<<2 * NROWS / 4, 256, 0, stream>>>(emb, qry, En, Qn, rowsum, out);
    k_simlse<<<32 * NSPLIT, 256, 0, stream>>>(En, Qn, rowsum, pickv);
    k_finalize<<<16, 256, 0, stream>>>(rowsum, pickv, out);
}